// Round 6
// baseline (484.372 us; speedup 1.0000x reference)
//
#include <hip/hip_runtime.h>
#include <math.h>

#define N 4096
#define THREADS 256
#define BATCH 8192
#define GRID 512                       // 2 blocks/CU, exactly resident (persistent)
#define ITERS ((BATCH / 4) / GRID)     // 4 row-groups per block

// XOR swizzle: bijection on [0,4096) making all three LDS access families
// (stride-256 reads, 16-contiguous writes, stride-16 writes) bank-minimal.
// MEASURED conflict-free (rounds 0/3/4/5: SQ_LDS_BANK_CONFLICT == 0) -- do not touch.
#define SWZ(i) ((i) ^ (((i) >> 4) & 15))
// dft16 stores X_p at slot IDX16(p) (base-4 digit swap; involution)
#define IDX16(p) ((((p) & 3) << 2) | ((p) >> 2))

__device__ __forceinline__ float2 cmul(float2 a, float2 b) {
    return make_float2(fmaf(a.x, b.x, -(a.y * b.y)), fmaf(a.x, b.y, a.y * b.x));
}

// radix-4 butterfly at v[base + r*stride]; forward uses w4 = -i, inverse +i
template<bool INV>
__device__ __forceinline__ void dft4(float2* v, int base, int stride) {
    float2 a = v[base], b = v[base + stride], c = v[base + 2 * stride], d = v[base + 3 * stride];
    float2 t0 = make_float2(a.x + c.x, a.y + c.y);
    float2 t1 = make_float2(a.x - c.x, a.y - c.y);
    float2 t2 = make_float2(b.x + d.x, b.y + d.y);
    float2 t3 = make_float2(b.x - d.x, b.y - d.y);
    float2 j3 = INV ? make_float2(-t3.y, t3.x) : make_float2(t3.y, -t3.x);
    v[base]              = make_float2(t0.x + t2.x, t0.y + t2.y);
    v[base + stride]     = make_float2(t1.x + j3.x, t1.y + j3.y);
    v[base + 2 * stride] = make_float2(t0.x - t2.x, t0.y - t2.y);
    v[base + 3 * stride] = make_float2(t1.x - j3.x, t1.y - j3.y);
}

// internal W16^{n1*k2} twiddles; slot set is symmetric under n1<->k2 so this
// works for both dft16 and dft16_perm.
template<bool INV>
__device__ __forceinline__ void tw16(float2* v) {
    const float C1 = 0.9238795325112867f;
    const float S1 = 0.3826834323650898f;
    const float R2 = 0.7071067811865476f;
    const float s = INV ? 1.0f : -1.0f;
    const float2 W1 = make_float2(C1, s * S1);
    const float2 W2 = make_float2(R2, s * R2);
    const float2 W3 = make_float2(S1, s * C1);
    const float2 W6 = make_float2(-R2, s * R2);
    const float2 W9 = make_float2(-C1, -s * S1);
    v[5]  = cmul(v[5],  W1);
    v[9]  = cmul(v[9],  W2);
    v[13] = cmul(v[13], W3);
    v[6]  = cmul(v[6],  W2);
    { float2 z = v[10]; v[10] = INV ? make_float2(-z.y, z.x) : make_float2(z.y, -z.x); }  // W4 = -/+ i
    v[14] = cmul(v[14], W6);
    v[7]  = cmul(v[7],  W3);
    v[11] = cmul(v[11], W6);
    v[15] = cmul(v[15], W9);
}

// input sample n at v[n]; output X_p at v[IDX16(p)]
template<bool INV>
__device__ __forceinline__ void dft16(float2* v) {
    #pragma unroll
    for (int n1 = 0; n1 < 4; ++n1) dft4<INV>(v, n1, 4);
    tw16<INV>(v);
    #pragma unroll
    for (int k2 = 0; k2 < 4; ++k2) dft4<INV>(v, 4 * k2, 1);
}

// input sample n at v[IDX16(n)]; output X_p at v[p]
template<bool INV>
__device__ __forceinline__ void dft16_perm(float2* v) {
    #pragma unroll
    for (int n1 = 0; n1 < 4; ++n1) dft4<INV>(v, 4 * n1, 1);
    tw16<INV>(v);
    #pragma unroll
    for (int k2 = 0; k2 < 4; ++k2) dft4<INV>(v, k2, 4);
}

// ---------------------------------------------------------------------------
// prep: full Hermitian spectrum H[0..N), twiddle table tw[0..N), and the
// TRANSPOSED stage-A twiddle table twA[p*256+t] = W_N^{t*p} (coalesced reads;
// measured win in round 3).
// ---------------------------------------------------------------------------
__global__ void prep_kernel(const float* __restrict__ wr, const float* __restrict__ wi,
                            float2* __restrict__ H, float2* __restrict__ tw) {
    int i = blockIdx.x * blockDim.x + threadIdx.x;
    if (i < N) {
        double ang = -2.0 * M_PI * (double)i / (double)N;
        tw[i] = make_float2((float)cos(ang), (float)sin(ang));
        float re, im;
        if (i <= N / 2) {
            re = wr[i];
            im = (i == N / 2) ? 0.0f : wi[i];
        } else {
            re = wr[N - i];
            im = -wi[N - i];
        }
        H[i] = make_float2(re, im);
    }
}

__global__ void prep_twA_kernel(float2* __restrict__ twA) {
    int i = blockIdx.x * blockDim.x + threadIdx.x;   // i in [0, 4096)
    int p = i >> 8, t = i & 255;
    double ang = -2.0 * M_PI * (double)(t * p) / (double)N;
    twA[i] = make_float2((float)cos(ang), (float)sin(ang));
}

// ---------------------------------------------------------------------------
// Persistent-block version of the measured-best round-4 kernel (106 us).
// 512 blocks (2/CU, all resident), each loops over ITERS=4 row-groups
// (group = 4 rows = 2 complex sequences za, zb). Per-iteration interval
// structure is BYTE-IDENTICAL to round 4 (lockstep A+B; r5 proved the
// compiler already extracts cross-sequence overlap, so no hand offsetting).
// The one structural change: stage S1 consumes a dedicated prefetch register
// set pa/pb, and the NEXT group's 32 global loads are issued right after
// S1's LDS writes -- they fly under the remaining ~25 us of pipeline, so
// the next iteration's S1 never waits on vmcnt and HBM traffic is smeared
// instead of bursting at block-generation boundaries (r4: HBM only 23%
// avg = bursty; load window fully exposed 4x).
// S2..S5 keep using va/vb -- they are refilled from LDS each stage anyway,
// so the register-identity split is free.
// Register audit (r1/r2 spill tripwire): 128 data VGPR + ~30 temps ~ 170;
// launch_bounds(256,2) -> 256 budget at 2 waves/SIMD. Spill tripwire =
// WRITE_SIZE >> 131 MB.
// ---------------------------------------------------------------------------
__global__ __launch_bounds__(THREADS, 2) void fft_conv_kernel(
        const float* __restrict__ x, const float2* __restrict__ H,
        const float2* __restrict__ tw, const float2* __restrict__ twA,
        const float* __restrict__ bias, float* __restrict__ out) {
    __shared__ float2 lds[2 * N];   // 64 KB
    float2* __restrict__ ldsA = lds;
    float2* __restrict__ ldsB = lds + N;
    const int t = threadIdx.x;
    const int k = t & 15, j = t >> 4;

    float2 pa[16], pb[16];   // prefetch + S1 working set
    float2 va[16], vb[16];   // S2..S5 working set (refilled from LDS per stage)

    long g = blockIdx.x;     // row-group index; strided by GRID per iteration

    // ---- prologue: load group 0 (pattern t+256r, coalesced) ----
    {
        const long b1 = (long)(4 * g) * N, b2 = b1 + N, b3 = b1 + 2 * N, b4 = b1 + 3 * N;
        #pragma unroll
        for (int r = 0; r < 16; ++r) {
            pa[r].x = x[b1 + t + 256 * r];
            pa[r].y = x[b2 + t + 256 * r];
        }
        #pragma unroll
        for (int r = 0; r < 16; ++r) {
            pb[r].x = x[b3 + t + 256 * r];
            pb[r].y = x[b4 + t + 256 * r];
        }
    }

    #pragma unroll 1
    for (int it = 0; it < ITERS; ++it) {
        const long b1 = (long)(4 * g) * N, b2 = b1 + N, b3 = b1 + 2 * N, b4 = b1 + 3 * N;

        // ======== S1 (fwd m=1) on prefetched regs ========
        dft16<false>(pa);
        dft16<false>(pb);
        #pragma unroll
        for (int p = 1; p < 16; ++p) {
            float2 w = twA[p * 256 + t];                 // coalesced, shared
            pa[IDX16(p)] = cmul(pa[IDX16(p)], w);
            pb[IDX16(p)] = cmul(pb[IDX16(p)], w);
        }
        #pragma unroll
        for (int p = 0; p < 16; ++p) ldsA[SWZ(16 * t + p)] = pa[IDX16(p)];
        #pragma unroll
        for (int p = 0; p < 16; ++p) ldsB[SWZ(16 * t + p)] = pb[IDX16(p)];

        // ---- issue next group's global loads; in flight across this iter ----
        if (it + 1 < ITERS) {
            const long ng = g + GRID;
            const long n1 = (long)(4 * ng) * N, n2 = n1 + N, n3 = n1 + 2 * N, n4 = n1 + 3 * N;
            #pragma unroll
            for (int r = 0; r < 16; ++r) {
                pa[r].x = x[n1 + t + 256 * r];
                pa[r].y = x[n2 + t + 256 * r];
            }
            #pragma unroll
            for (int r = 0; r < 16; ++r) {
                pb[r].x = x[n3 + t + 256 * r];
                pb[r].y = x[n4 + t + 256 * r];
            }
        }
        __syncthreads();                                            // (1)

        // ======== S2 (fwd m=16): R, |s|, compute, W ========
        #pragma unroll
        for (int r = 0; r < 16; ++r) va[r] = ldsA[SWZ(t + 256 * r)];
        #pragma unroll
        for (int r = 0; r < 16; ++r) vb[r] = ldsB[SWZ(t + 256 * r)];
        __syncthreads();                                            // (2)
        dft16<false>(va);
        dft16<false>(vb);
        #pragma unroll
        for (int p = 1; p < 16; ++p) {
            float2 w = tw[16 * j * p];                   // 4-address broadcast, shared
            va[IDX16(p)] = cmul(va[IDX16(p)], w);
            vb[IDX16(p)] = cmul(vb[IDX16(p)], w);
        }
        #pragma unroll
        for (int p = 0; p < 16; ++p) ldsA[SWZ(k + 256 * j + 16 * p)] = va[IDX16(p)];
        #pragma unroll
        for (int p = 0; p < 16; ++p) ldsB[SWZ(k + 256 * j + 16 * p)] = vb[IDX16(p)];
        __syncthreads();                                            // (3)

        // ======== S3 (fwd m=256 + H + inv m=1, fused in regs) ========
        #pragma unroll
        for (int r = 0; r < 16; ++r) va[r] = ldsA[SWZ(t + 256 * r)];
        #pragma unroll
        for (int r = 0; r < 16; ++r) vb[r] = ldsB[SWZ(t + 256 * r)];
        __syncthreads();                                            // (4)
        dft16<false>(va);
        dft16<false>(vb);
        // slot q holds spectrum element at natural index t + 256*IDX16(q)
        #pragma unroll
        for (int q = 0; q < 16; ++q) {
            float2 h = H[t + 256 * IDX16(q)];            // coalesced, shared
            va[q] = cmul(va[q], h);
            vb[q] = cmul(vb[q], h);
        }
        dft16_perm<true>(va);                            // X_p at slot p
        dft16_perm<true>(vb);
        #pragma unroll
        for (int p = 1; p < 16; ++p) {
            float2 w = twA[p * 256 + t]; w.y = -w.y;     // conj, coalesced, shared
            va[p] = cmul(va[p], w);
            vb[p] = cmul(vb[p], w);
        }
        #pragma unroll
        for (int p = 0; p < 16; ++p) ldsA[SWZ(16 * t + p)] = va[p];
        #pragma unroll
        for (int p = 0; p < 16; ++p) ldsB[SWZ(16 * t + p)] = vb[p];
        __syncthreads();                                            // (5)

        // ======== S4 (inv m=16) ========
        #pragma unroll
        for (int r = 0; r < 16; ++r) va[r] = ldsA[SWZ(t + 256 * r)];
        #pragma unroll
        for (int r = 0; r < 16; ++r) vb[r] = ldsB[SWZ(t + 256 * r)];
        __syncthreads();                                            // (6)
        dft16<true>(va);
        dft16<true>(vb);
        #pragma unroll
        for (int p = 1; p < 16; ++p) {
            float2 w = tw[16 * j * p]; w.y = -w.y;
            va[IDX16(p)] = cmul(va[IDX16(p)], w);
            vb[IDX16(p)] = cmul(vb[IDX16(p)], w);
        }
        #pragma unroll
        for (int p = 0; p < 16; ++p) ldsA[SWZ(k + 256 * j + 16 * p)] = va[IDX16(p)];
        #pragma unroll
        for (int p = 0; p < 16; ++p) ldsB[SWZ(k + 256 * j + 16 * p)] = vb[IDX16(p)];
        __syncthreads();                                            // (7)

        // ======== S5 (inv m=256) + scale/bias epilogue to global ========
        #pragma unroll
        for (int r = 0; r < 16; ++r) va[r] = ldsA[SWZ(t + 256 * r)];
        #pragma unroll
        for (int r = 0; r < 16; ++r) vb[r] = ldsB[SWZ(t + 256 * r)];
        dft16<true>(va);
        dft16<true>(vb);
        const float inv = 1.0f / (float)N;
        #pragma unroll
        for (int p = 0; p < 16; ++p) {
            float2 a = va[IDX16(p)];
            float2 b = vb[IDX16(p)];
            float bb = bias[t + 256 * p];                // one load, four uses
            out[b1 + t + 256 * p] = fmaf(a.x, inv, bb);
            out[b2 + t + 256 * p] = fmaf(a.y, inv, bb);
            out[b3 + t + 256 * p] = fmaf(b.x, inv, bb);
            out[b4 + t + 256 * p] = fmaf(b.y, inv, bb);
        }
        __syncthreads();                                            // (8) LDS WAR vs next-iter S1
        g += GRID;
    }
}

// ---------------------------------------------------------------------------
extern "C" void kernel_launch(void* const* d_in, const int* in_sizes, int n_in,
                              void* d_out, int out_size, void* d_ws, size_t ws_size,
                              hipStream_t stream) {
    const float* x  = (const float*)d_in[0];   // (8192, 4096)
    const float* wr = (const float*)d_in[1];   // (2049,)
    const float* wi = (const float*)d_in[2];   // (2049,)
    const float* bs = (const float*)d_in[3];   // (4096,)
    float* out = (float*)d_out;                // (8192, 4096)

    float2* H   = (float2*)d_ws;                                           // 32 KB
    float2* tw  = (float2*)((char*)d_ws + (size_t)N * sizeof(float2));     // 32 KB
    float2* twA = (float2*)((char*)d_ws + (size_t)2 * N * sizeof(float2)); // 32 KB

    prep_kernel<<<dim3(N / THREADS), dim3(THREADS), 0, stream>>>(wr, wi, H, tw);
    prep_twA_kernel<<<dim3(N / THREADS), dim3(THREADS), 0, stream>>>(twA);
    fft_conv_kernel<<<dim3(GRID), dim3(THREADS), 0, stream>>>(x, H, tw, twA, bs, out);
}

// Round 7
// 261.274 us; speedup vs baseline: 1.8539x; 1.8539x over previous
//
#include <hip/hip_runtime.h>
#include <math.h>

#define N 4096
#define THREADS 256
#define BATCH 8192

// XOR swizzle: bijection on [0,4096) making all three LDS access families
// (stride-256 reads, 16-contiguous writes, stride-16 writes) bank-minimal.
// MEASURED conflict-free (rounds 0/3/4/5, b64). For the b128 packed layout all
// three families spread 64 lanes uniformly over the 8 four-bank groups
// (8 lanes/group = 2 words/bank vs the 4-cyc b128 floor -- the m136 "free"
// regime). Tripwire: SQ_LDS_BANK_CONFLICT.
#define SWZ(i) ((i) ^ (((i) >> 4) & 15))
// dft16 stores X_p at slot IDX16(p) (base-4 digit swap; involution)
#define IDX16(p) ((((p) & 3) << 2) | ((p) >> 2))

__device__ __forceinline__ float2 cmul(float2 a, float2 b) {
    return make_float2(fmaf(a.x, b.x, -(a.y * b.y)), fmaf(a.x, b.y, a.y * b.x));
}

// radix-4 butterfly at v[base + r*stride]; forward uses w4 = -i, inverse +i
template<bool INV>
__device__ __forceinline__ void dft4(float2* v, int base, int stride) {
    float2 a = v[base], b = v[base + stride], c = v[base + 2 * stride], d = v[base + 3 * stride];
    float2 t0 = make_float2(a.x + c.x, a.y + c.y);
    float2 t1 = make_float2(a.x - c.x, a.y - c.y);
    float2 t2 = make_float2(b.x + d.x, b.y + d.y);
    float2 t3 = make_float2(b.x - d.x, b.y - d.y);
    float2 j3 = INV ? make_float2(-t3.y, t3.x) : make_float2(t3.y, -t3.x);
    v[base]              = make_float2(t0.x + t2.x, t0.y + t2.y);
    v[base + stride]     = make_float2(t1.x + j3.x, t1.y + j3.y);
    v[base + 2 * stride] = make_float2(t0.x - t2.x, t0.y - t2.y);
    v[base + 3 * stride] = make_float2(t1.x - j3.x, t1.y - j3.y);
}

// internal W16^{n1*k2} twiddles; slot set is symmetric under n1<->k2 so this
// works for both dft16 and dft16_perm.
template<bool INV>
__device__ __forceinline__ void tw16(float2* v) {
    const float C1 = 0.9238795325112867f;
    const float S1 = 0.3826834323650898f;
    const float R2 = 0.7071067811865476f;
    const float s = INV ? 1.0f : -1.0f;
    const float2 W1 = make_float2(C1, s * S1);
    const float2 W2 = make_float2(R2, s * R2);
    const float2 W3 = make_float2(S1, s * C1);
    const float2 W6 = make_float2(-R2, s * R2);
    const float2 W9 = make_float2(-C1, -s * S1);
    v[5]  = cmul(v[5],  W1);
    v[9]  = cmul(v[9],  W2);
    v[13] = cmul(v[13], W3);
    v[6]  = cmul(v[6],  W2);
    { float2 z = v[10]; v[10] = INV ? make_float2(-z.y, z.x) : make_float2(z.y, -z.x); }  // W4 = -/+ i
    v[14] = cmul(v[14], W6);
    v[7]  = cmul(v[7],  W3);
    v[11] = cmul(v[11], W6);
    v[15] = cmul(v[15], W9);
}

// input sample n at v[n]; output X_p at v[IDX16(p)]
template<bool INV>
__device__ __forceinline__ void dft16(float2* v) {
    #pragma unroll
    for (int n1 = 0; n1 < 4; ++n1) dft4<INV>(v, n1, 4);
    tw16<INV>(v);
    #pragma unroll
    for (int k2 = 0; k2 < 4; ++k2) dft4<INV>(v, 4 * k2, 1);
}

// input sample n at v[IDX16(n)]; output X_p at v[p]
template<bool INV>
__device__ __forceinline__ void dft16_perm(float2* v) {
    #pragma unroll
    for (int n1 = 0; n1 < 4; ++n1) dft4<INV>(v, 4 * n1, 1);
    tw16<INV>(v);
    #pragma unroll
    for (int k2 = 0; k2 < 4; ++k2) dft4<INV>(v, k2, 4);
}

// ---------------------------------------------------------------------------
// prep: full Hermitian spectrum H[0..N), twiddle table tw[0..N), and the
// TRANSPOSED stage-A twiddle table twA[p*256+t] = W_N^{t*p} (coalesced reads;
// measured win in round 3).
// ---------------------------------------------------------------------------
__global__ void prep_kernel(const float* __restrict__ wr, const float* __restrict__ wi,
                            float2* __restrict__ H, float2* __restrict__ tw) {
    int i = blockIdx.x * blockDim.x + threadIdx.x;
    if (i < N) {
        double ang = -2.0 * M_PI * (double)i / (double)N;
        tw[i] = make_float2((float)cos(ang), (float)sin(ang));
        float re, im;
        if (i <= N / 2) {
            re = wr[i];
            im = (i == N / 2) ? 0.0f : wi[i];
        } else {
            re = wr[N - i];
            im = -wi[N - i];
        }
        H[i] = make_float2(re, im);
    }
}

__global__ void prep_twA_kernel(float2* __restrict__ twA) {
    int i = blockIdx.x * blockDim.x + threadIdx.x;   // i in [0, 4096)
    int p = i >> 8, t = i & 255;
    double ang = -2.0 * M_PI * (double)(t * p) / (double)N;
    twA[i] = make_float2((float)cos(ang), (float)sin(ang));
}

// ---------------------------------------------------------------------------
// One block = 4 rows = TWO independent complex sequences (za = r0 + i*r1,
// zb = r2 + i*r3), lockstep (round-4 structure, measured 106 us -- best).
// Round-7 change: the two sequences use IDENTICAL LDS indices everywhere,
// so pack them -- lds[i] = (A[i].re, A[i].im, B[i].re, B[i].im) as float4.
// Every b64 read/write pair becomes ONE b128 op: per-thread LDS ops
// 256 -> 128 and half the SWZ address computations vanish (~380 VALU
// instrs/thread). Same bytes, same indices, same barriers, zero added
// register state (r6 post-mortem: any long-lived extra regs spill).
// Spill tripwire: WRITE_SIZE >> 131 MB. Conflict tripwire: SQ_LDS_BANK_CONFLICT.
// ---------------------------------------------------------------------------
__global__ __launch_bounds__(THREADS, 2) void fft_conv_kernel(
        const float* __restrict__ x, const float2* __restrict__ H,
        const float2* __restrict__ tw, const float2* __restrict__ twA,
        const float* __restrict__ bias, float* __restrict__ out) {
    __shared__ float4 lds[N];   // 64 KB, packed (seqA, seqB)
    const int t = threadIdx.x;
    const int k = t & 15, j = t >> 4;
    const long base1 = (long)(4 * blockIdx.x) * N;  // row 4b
    const long base2 = base1 + N;                   // row 4b+1
    const long base3 = base1 + 2 * N;               // row 4b+2
    const long base4 = base1 + 3 * N;               // row 4b+3

    float2 va[16], vb[16];

    // ---- load both sequences: pattern t+256r, coalesced ----
    #pragma unroll
    for (int r = 0; r < 16; ++r) {
        va[r].x = x[base1 + t + 256 * r];
        va[r].y = x[base2 + t + 256 * r];
    }
    #pragma unroll
    for (int r = 0; r < 16; ++r) {
        vb[r].x = x[base3 + t + 256 * r];
        vb[r].y = x[base4 + t + 256 * r];
    }

    // ---- fwd A (m=1): twiddle w^(t*p) from transposed table, shared ----
    dft16<false>(va);
    dft16<false>(vb);
    #pragma unroll
    for (int p = 1; p < 16; ++p) {
        float2 w = twA[p * 256 + t];                 // coalesced, one load, two uses
        va[IDX16(p)] = cmul(va[IDX16(p)], w);
        vb[IDX16(p)] = cmul(vb[IDX16(p)], w);
    }
    #pragma unroll
    for (int p = 0; p < 16; ++p) {
        float2 a = va[IDX16(p)], b = vb[IDX16(p)];
        lds[SWZ(16 * t + p)] = make_float4(a.x, a.y, b.x, b.y);
    }
    __syncthreads();

    // ---- fwd B (m=16): read t+256r, twiddle w^(16jp), write k+256j+16p ----
    #pragma unroll
    for (int r = 0; r < 16; ++r) {
        float4 q = lds[SWZ(t + 256 * r)];
        va[r] = make_float2(q.x, q.y);
        vb[r] = make_float2(q.z, q.w);
    }
    __syncthreads();                                // reads before in-place writes
    dft16<false>(va);
    dft16<false>(vb);
    #pragma unroll
    for (int p = 1; p < 16; ++p) {
        float2 w = tw[16 * j * p];                   // 4-address broadcast, shared
        va[IDX16(p)] = cmul(va[IDX16(p)], w);
        vb[IDX16(p)] = cmul(vb[IDX16(p)], w);
    }
    #pragma unroll
    for (int p = 0; p < 16; ++p) {
        float2 a = va[IDX16(p)], b = vb[IDX16(p)];
        lds[SWZ(k + 256 * j + 16 * p)] = make_float4(a.x, a.y, b.x, b.y);
    }
    __syncthreads();

    // ---- fwd C (m=256, no twiddle) + pointwise H, all in registers ----
    #pragma unroll
    for (int r = 0; r < 16; ++r) {
        float4 q = lds[SWZ(t + 256 * r)];
        va[r] = make_float2(q.x, q.y);
        vb[r] = make_float2(q.z, q.w);
    }
    __syncthreads();                                // protect inv-A writes below
    dft16<false>(va);
    dft16<false>(vb);
    // slot q holds spectrum element at natural index t + 256*IDX16(q)
    #pragma unroll
    for (int q = 0; q < 16; ++q) {
        float2 h = H[t + 256 * IDX16(q)];            // coalesced, shared
        va[q] = cmul(va[q], h);
        vb[q] = cmul(vb[q], h);
    }

    // ---- inv A (m=1): input IDX16-permuted in regs -> dft16_perm ----
    dft16_perm<true>(va);                           // output X_p at slot p
    dft16_perm<true>(vb);
    #pragma unroll
    for (int p = 1; p < 16; ++p) {
        float2 w = twA[p * 256 + t]; w.y = -w.y;     // conj, coalesced, shared
        va[p] = cmul(va[p], w);
        vb[p] = cmul(vb[p], w);
    }
    #pragma unroll
    for (int p = 0; p < 16; ++p)
        lds[SWZ(16 * t + p)] = make_float4(va[p].x, va[p].y, vb[p].x, vb[p].y);
    __syncthreads();

    // ---- inv B (m=16) ----
    #pragma unroll
    for (int r = 0; r < 16; ++r) {
        float4 q = lds[SWZ(t + 256 * r)];
        va[r] = make_float2(q.x, q.y);
        vb[r] = make_float2(q.z, q.w);
    }
    __syncthreads();
    dft16<true>(va);
    dft16<true>(vb);
    #pragma unroll
    for (int p = 1; p < 16; ++p) {
        float2 w = tw[16 * j * p]; w.y = -w.y;
        va[IDX16(p)] = cmul(va[IDX16(p)], w);
        vb[IDX16(p)] = cmul(vb[IDX16(p)], w);
    }
    #pragma unroll
    for (int p = 0; p < 16; ++p) {
        float2 a = va[IDX16(p)], b = vb[IDX16(p)];
        lds[SWZ(k + 256 * j + 16 * p)] = make_float4(a.x, a.y, b.x, b.y);
    }
    __syncthreads();

    // ---- inv C (m=256) + scale/bias epilogue straight to global ----
    #pragma unroll
    for (int r = 0; r < 16; ++r) {
        float4 q = lds[SWZ(t + 256 * r)];
        va[r] = make_float2(q.x, q.y);
        vb[r] = make_float2(q.z, q.w);
    }
    dft16<true>(va);
    dft16<true>(vb);
    const float inv = 1.0f / (float)N;
    #pragma unroll
    for (int p = 0; p < 16; ++p) {
        float2 a = va[IDX16(p)];
        float2 b = vb[IDX16(p)];
        float bb = bias[t + 256 * p];                // one load, four uses
        out[base1 + t + 256 * p] = fmaf(a.x, inv, bb);
        out[base2 + t + 256 * p] = fmaf(a.y, inv, bb);
        out[base3 + t + 256 * p] = fmaf(b.x, inv, bb);
        out[base4 + t + 256 * p] = fmaf(b.y, inv, bb);
    }
}

// ---------------------------------------------------------------------------
extern "C" void kernel_launch(void* const* d_in, const int* in_sizes, int n_in,
                              void* d_out, int out_size, void* d_ws, size_t ws_size,
                              hipStream_t stream) {
    const float* x  = (const float*)d_in[0];   // (8192, 4096)
    const float* wr = (const float*)d_in[1];   // (2049,)
    const float* wi = (const float*)d_in[2];   // (2049,)
    const float* bs = (const float*)d_in[3];   // (4096,)
    float* out = (float*)d_out;                // (8192, 4096)

    float2* H   = (float2*)d_ws;                                           // 32 KB
    float2* tw  = (float2*)((char*)d_ws + (size_t)N * sizeof(float2));     // 32 KB
    float2* twA = (float2*)((char*)d_ws + (size_t)2 * N * sizeof(float2)); // 32 KB

    prep_kernel<<<dim3(N / THREADS), dim3(THREADS), 0, stream>>>(wr, wi, H, tw);
    prep_twA_kernel<<<dim3(N / THREADS), dim3(THREADS), 0, stream>>>(twA);
    fft_conv_kernel<<<dim3(BATCH / 4), dim3(THREADS), 0, stream>>>(x, H, tw, twA, bs, out);
}